// Round 2
// baseline (383.908 us; speedup 1.0000x reference)
//
#include <hip/hip_runtime.h>
#include <math.h>

#define H 4096
#define NE 64
#define KTOP 8
#define BT 64
#define KC 32
#define TTOT 16384
#define NBLK (TTOT / BT)   // 256

struct __align__(16) SmemT {
  union {
    struct { float xs[64][36]; float we[64][36]; };  // fp32 staging (18432 B)
    double lgd[64 * 66];                             // fp64 logits (33792 B)
  };
  float msum[4][64];
  float cnt[4][64];
};

__global__ __launch_bounds__(256) void moe_gate_main(
    const float* __restrict__ x, const float* __restrict__ w,
    float* __restrict__ out, float* __restrict__ wsg) {
  __shared__ SmemT sm;
  const int tid = threadIdx.x;
  const int bid = blockIdx.x;
  const int tok0 = bid * BT;

  const int tr = tid >> 4;                 // token group 0..15 (4 tokens each)
  const int tc = tid & 15;                 // expert group 0..15 (4 experts each)
  const int swz = ((tc >> 1) & 7) << 2;    // read-side quad swizzle

  // staging mapping: each thread loads 8 floats of one row (x) + one row (w)
  const int ldrow = tid >> 2;              // 0..63
  const int ldcol = (tid & 3) * 8;         // 0,8,16,24
  const int wswz = ((ldrow >> 3) & 7) << 2;
  const float* xp = x + (size_t)(tok0 + ldrow) * H + ldcol;
  const float* wp = w + (size_t)ldrow * H + ldcol;

  double acc[4][4];
#pragma unroll
  for (int i = 0; i < 4; ++i)
#pragma unroll
    for (int j = 0; j < 4; ++j) acc[i][j] = 0.0;

  // prologue: stage chunk 0
  {
    float4 a0 = *(const float4*)(xp);
    float4 a1 = *(const float4*)(xp + 4);
    float4 b0 = *(const float4*)(wp);
    float4 b1 = *(const float4*)(wp + 4);
    *(float4*)&sm.xs[ldrow][ldcol] = a0;
    *(float4*)&sm.xs[ldrow][ldcol + 4] = a1;
    *(float4*)&sm.we[ldrow][ldcol ^ wswz] = b0;
    *(float4*)&sm.we[ldrow][(ldcol + 4) ^ wswz] = b1;
  }
  __syncthreads();

#define KSTEP(C)                                                          \
  do {                                                                    \
    double xd[4], wd[4];                                                  \
    xd[0] = (double)xv[0].C; xd[1] = (double)xv[1].C;                     \
    xd[2] = (double)xv[2].C; xd[3] = (double)xv[3].C;                     \
    wd[0] = (double)wv[0].C; wd[1] = (double)wv[1].C;                     \
    wd[2] = (double)wv[2].C; wd[3] = (double)wv[3].C;                     \
    _Pragma("unroll") for (int i = 0; i < 4; ++i)                         \
      _Pragma("unroll") for (int j = 0; j < 4; ++j)                       \
        acc[i][j] = fma(xd[i], wd[j], acc[i][j]);                         \
  } while (0)

#pragma unroll 1
  for (int c = 0; c < H / KC; ++c) {
    float4 a0, a1, b0, b1;
    const bool more = (c + 1) < (H / KC);
    if (more) {  // register prefetch of next chunk (latency hidden under FMAs)
      const float* xq = xp + (c + 1) * KC;
      const float* wq = wp + (c + 1) * KC;
      a0 = *(const float4*)(xq);
      a1 = *(const float4*)(xq + 4);
      b0 = *(const float4*)(wq);
      b1 = *(const float4*)(wq + 4);
    }
#pragma unroll
    for (int kq = 0; kq < 8; ++kq) {
      float4 xv[4], wv[4];
#pragma unroll
      for (int i = 0; i < 4; ++i)
        xv[i] = *(const float4*)&sm.xs[tr * 4 + i][kq * 4];
#pragma unroll
      for (int j = 0; j < 4; ++j)
        wv[j] = *(const float4*)&sm.we[tc * 4 + j][(kq * 4) ^ swz];
      KSTEP(x); KSTEP(y); KSTEP(z); KSTEP(w);
    }
    __syncthreads();
    if (more) {
      *(float4*)&sm.xs[ldrow][ldcol] = a0;
      *(float4*)&sm.xs[ldrow][ldcol + 4] = a1;
      *(float4*)&sm.we[ldrow][ldcol ^ wswz] = b0;
      *(float4*)&sm.we[ldrow][(ldcol + 4) ^ wswz] = b1;
    }
    __syncthreads();
  }

  // spill fp64 logits to LDS (reuses staging memory; all staging reads done)
#pragma unroll
  for (int i = 0; i < 4; ++i)
#pragma unroll
    for (int j = 0; j < 4; ++j)
      sm.lgd[(tr * 4 + i) * 66 + tc * 4 + j] = acc[i][j];
  __syncthreads();

  // epilogue: one wave per token, lane = expert
  const int lane = tid & 63;
  const int wid = tid >> 6;
  float msum = 0.f;
  int cnt = 0;

#pragma unroll 1
  for (int it = 0; it < 16; ++it) {
    const int t = wid * 16 + it;
    double l = sm.lgd[t * 66 + lane];

    // fp32 softmax over 64 experts — for aux-loss partials only
    float lf = (float)l;
    float m = lf;
#pragma unroll
    for (int off = 32; off; off >>= 1) m = fmaxf(m, __shfl_xor(m, off));
    float p = expf(lf - m);
    float s = p;
#pragma unroll
    for (int off = 32; off; off >>= 1) s += __shfl_xor(s, off);
    msum += p / s;

    // top-8 by fp64 logit (== score order; softmax is monotone),
    // descending, ties -> lowest index (matches jax.lax.top_k)
    double cur = l;
    double myv = 0.0;
    int myi = 0;
#pragma unroll
    for (int r = 0; r < KTOP; ++r) {
      double v = cur;
      int ix = lane;
#pragma unroll
      for (int off = 1; off < 64; off <<= 1) {
        double ov = __shfl_xor(v, off);
        int oi = __shfl_xor(ix, off);
        if (ov > v || (ov == v && oi < ix)) { v = ov; ix = oi; }
      }
      if (lane == r) { myv = v; myi = ix; }
      if (lane == ix) { cur = -INFINITY; ++cnt; }
    }
    // weights: exp(l_i - m0)/sum_top8 — full softmax denominator cancels.
    // lanes 0..7 hold the winners (rank 0 = max logit).
    double m0 = __shfl(myv, 0);
    float e = expf((float)(myv - m0));
    float sv = e;
    sv += __shfl_xor(sv, 1);
    sv += __shfl_xor(sv, 2);
    sv += __shfl_xor(sv, 4);
    float wgt = e / sv;
    const int tg = tok0 + t;
    if (lane < KTOP) {
      out[(size_t)tg * KTOP + lane] = (float)myi;
      out[(size_t)TTOT * KTOP + (size_t)tg * KTOP + lane] = wgt;
    }
  }

  // per-block aux partials (deterministic, no atomics)
  sm.msum[wid][lane] = msum;
  sm.cnt[wid][lane] = (float)cnt;
  __syncthreads();
  if (tid < 64) {
    float c4 = sm.cnt[0][tid] + sm.cnt[1][tid] + sm.cnt[2][tid] + sm.cnt[3][tid];
    float m4 = sm.msum[0][tid] + sm.msum[1][tid] + sm.msum[2][tid] + sm.msum[3][tid];
    wsg[bid * 128 + tid] = c4;
    wsg[bid * 128 + 64 + tid] = m4;
  }
}

// aux = alpha * mean_b sum_e (count[b,e]/(S*K/E)) * (scoresum[b,e]/S)
__global__ __launch_bounds__(256) void moe_gate_aux(
    const float* __restrict__ wsg, float* __restrict__ out) {
  const int tid = threadIdx.x;
  const int b = tid >> 6, e = tid & 63;
  float cnt = 0.f, ms = 0.f;
#pragma unroll 4
  for (int j = 0; j < 64; ++j) {
    const int blk = b * 64 + j;
    cnt += wsg[blk * 128 + e];
    ms += wsg[blk * 128 + 64 + e];
  }
  float term = (cnt * (1.f / 512.f)) * (ms * (1.f / 4096.f));
  __shared__ float red[4];
#pragma unroll
  for (int off = 32; off; off >>= 1) term += __shfl_xor(term, off);
  if ((tid & 63) == 0) red[tid >> 6] = term;
  __syncthreads();
  if (tid == 0) {
    float tot = red[0] + red[1] + red[2] + red[3];
    out[(size_t)TTOT * KTOP * 2] = tot * (0.001f / 4.f);
  }
}

extern "C" void kernel_launch(void* const* d_in, const int* in_sizes, int n_in,
                              void* d_out, int out_size, void* d_ws, size_t ws_size,
                              hipStream_t stream) {
  (void)in_sizes; (void)n_in; (void)out_size; (void)ws_size;
  const float* x = (const float*)d_in[0];
  const float* w = (const float*)d_in[1];
  float* out = (float*)d_out;
  float* wsf = (float*)d_ws;
  moe_gate_main<<<NBLK, 256, 0, stream>>>(x, w, out, wsf);
  moe_gate_aux<<<1, 256, 0, stream>>>(wsf, out);
}